// Round 1
// baseline (195.786 us; speedup 1.0000x reference)
//
#include <hip/hip_runtime.h>

// PercolationM: per-batch-element 256-bin histogram of [B,256,32,32] int32,
// output max bin count per batch element as float32. B=128, N=262144/batch.
//
// Round 3 strategy (vs R2): single fused dispatch, zero workspace use.
//   Timed region is dominated by two fixed ~78us harness ws-poison fills
//   (512 MiB each); the controllable portion is ~32us vs a ~21us read floor.
//   Fuse k1+k2: one block per batch element (128 blocks x 1024 thr). Each
//   block builds the full histogram for its batch element in bank-exclusive
//   32-replica LDS (lane i -> bank i%32, zero conflicts), replica-sums,
//   block-max-reduces, and writes out[b] directly. Removes the k2 dispatch,
//   its launch gap, and the 512 KiB partial round-trip through ws.
//   BW hedge: 128 blocks spread 16/XCD -> same per-XCD HBM share as the old
//   512-block layout; unroll 8 keeps 8 int4 loads in flight per thread to
//   cover HBM latency at the higher per-CU BW requirement.

#define NUM_BINS 256
#define NREP     32                // sub-histogram replicas (one per bank)
#define BLOCK    1024
#define N_PER_B  (256 * 32 * 32)   // 262144 elements per batch element

__global__ __launch_bounds__(BLOCK) void
percolation_fused_kernel(const int* __restrict__ in, float* __restrict__ out) {
    __shared__ int lh[NUM_BINS * NREP];   // 32 KiB

    for (int i = threadIdx.x; i < NUM_BINS * NREP; i += BLOCK)
        lh[i] = 0;
    __syncthreads();

    const int lane = threadIdx.x & (NREP - 1);    // bank-exclusive replica id

    const int4* p = (const int4*)(in + (size_t)blockIdx.x * N_PER_B);
    const int iters = N_PER_B / 4 / BLOCK;        // 64

#pragma unroll 8
    for (int i = 0; i < iters; ++i) {
        int4 v = p[(size_t)i * BLOCK + threadIdx.x];
        atomicAdd(&lh[v.x * NREP + lane], 1);
        atomicAdd(&lh[v.y * NREP + lane], 1);
        atomicAdd(&lh[v.z * NREP + lane], 1);
        atomicAdd(&lh[v.w * NREP + lane], 1);
    }
    __syncthreads();

    // Threads 0..255: sum 32 replicas per bin with rotated replica index
    // ((j+tid)&31 -> all lanes of a wave hit distinct banks). Threads >=256
    // contribute 0 to the max (all counts are >= 0, so harmless).
    int s = 0;
    if (threadIdx.x < NUM_BINS) {
#pragma unroll
        for (int j = 0; j < NREP; ++j)
            s += lh[threadIdx.x * NREP + ((j + threadIdx.x) & (NREP - 1))];
    }

    // block-wide max reduce
#pragma unroll
    for (int off = 32; off > 0; off >>= 1)
        s = max(s, __shfl_down(s, off, 64));

    __shared__ int wmax[BLOCK / 64];
    if ((threadIdx.x & 63) == 0)
        wmax[threadIdx.x >> 6] = s;
    __syncthreads();

    if (threadIdx.x == 0) {
        int m = wmax[0];
#pragma unroll
        for (int w = 1; w < BLOCK / 64; ++w)
            m = max(m, wmax[w]);
        out[blockIdx.x] = (float)m;
    }
}

extern "C" void kernel_launch(void* const* d_in, const int* in_sizes, int n_in,
                              void* d_out, int out_size, void* d_ws, size_t ws_size,
                              hipStream_t stream) {
    const int* in  = (const int*)d_in[0];
    float*     out = (float*)d_out;
    const int B = out_size;         // 128

    percolation_fused_kernel<<<B, BLOCK, 0, stream>>>(in, out);
}